// Round 7
// baseline (526.715 us; speedup 1.0000x reference)
//
#include <hip/hip_runtime.h>

#define N_NODES 50000
#define N_EDGES 800000
#define R_REL   8
#define NR      (N_NODES * R_REL)        // 400000
#define SCAN_CHUNK 2048
#define SCAN_NBLK  ((NR + SCAN_CHUNK - 1) / SCAN_CHUNK)   // 196

#define NCHUNK  25000                    // nodes per chunk (2 chunks)
#define CPAIRS  (NCHUNK * R_REL)         // 200000 pairs per chunk

typedef float  f32x4  __attribute__((ext_vector_type(4)));
typedef __bf16 bf16x8 __attribute__((ext_vector_type(8)));

__device__ __forceinline__ unsigned short f2bf(float f) {
    unsigned int u = __float_as_uint(f);
    u = (u + 0x7FFFu + ((u >> 16) & 1u)) >> 16;   // RNE
    return (unsigned short)u;
}
__device__ __forceinline__ float bflo(unsigned int u) { return __uint_as_float(u << 16); }
__device__ __forceinline__ float bfhi(unsigned int u) { return __uint_as_float(u & 0xFFFF0000u); }

__device__ __forceinline__ void acc16(float* a, uint4 u0, uint4 u1) {
    a[0]  += bflo(u0.x);   a[1]  += bfhi(u0.x);
    a[2]  += bflo(u0.y);   a[3]  += bfhi(u0.y);
    a[4]  += bflo(u0.z);   a[5]  += bfhi(u0.z);
    a[6]  += bflo(u0.w);   a[7]  += bfhi(u0.w);
    a[8]  += bflo(u1.x);   a[9]  += bfhi(u1.x);
    a[10] += bflo(u1.y);   a[11] += bfhi(u1.y);
    a[12] += bflo(u1.z);   a[13] += bfhi(u1.z);
    a[14] += bflo(u1.w);   a[15] += bfhi(u1.w);
}

// ---------------- CSR build ----------------

__global__ void k_hist(const int* __restrict__ dst, const int* __restrict__ et,
                       int* __restrict__ cnt) {
    int e = blockIdx.x * 256 + threadIdx.x;
    if (e < N_EDGES) atomicAdd(&cnt[dst[e] * R_REL + et[e]], 1);
}

__global__ void k_scan1(const int* __restrict__ cnt, int* __restrict__ offs,
                        int* __restrict__ bsum) {
    __shared__ int sd[256];
    int t = threadIdx.x;
    int base = blockIdx.x * SCAN_CHUNK + t * 8;
    int v[8];
    int tot = 0;
#pragma unroll
    for (int i = 0; i < 8; i++) {
        int idx = base + i;
        int xv = (idx < NR) ? cnt[idx] : 0;
        v[i] = tot;
        tot += xv;
    }
    sd[t] = tot;
    __syncthreads();
    for (int off = 1; off < 256; off <<= 1) {
        int y = (t >= off) ? sd[t - off] : 0;
        __syncthreads();
        sd[t] += y;
        __syncthreads();
    }
    int excl = sd[t] - tot;
#pragma unroll
    for (int i = 0; i < 8; i++) {
        int idx = base + i;
        if (idx < NR) offs[idx] = v[i] + excl;
    }
    if (t == 255) bsum[blockIdx.x] = sd[255];
}

__global__ void k_scan2(const int* __restrict__ bsum, int* __restrict__ bsum2) {
    __shared__ int sd[256];
    int t = threadIdx.x;
    int v = (t < SCAN_NBLK) ? bsum[t] : 0;
    sd[t] = v;
    __syncthreads();
    for (int off = 1; off < 256; off <<= 1) {
        int y = (t >= off) ? sd[t - off] : 0;
        __syncthreads();
        sd[t] += y;
        __syncthreads();
    }
    bsum2[t] = sd[t] - v;
}

__global__ void k_scan3(int* __restrict__ offs, const int* __restrict__ bsum2,
                        int* __restrict__ cursor) {
    int t = threadIdx.x;
    int b = blockIdx.x;
    int add = bsum2[b];
    int base = b * SCAN_CHUNK + t * 8;
#pragma unroll
    for (int i = 0; i < 8; i++) {
        int idx = base + i;
        if (idx < NR) {
            int v = offs[idx] + add;
            offs[idx] = v;
            cursor[idx] = v;
        }
    }
    if (b == 0 && t == 0) offs[NR] = N_EDGES;
}

__global__ void k_scatter(const int* __restrict__ src, const int* __restrict__ dst,
                          const int* __restrict__ et, int* __restrict__ cursor,
                          int* __restrict__ srcS) {
    int e = blockIdx.x * 256 + threadIdx.x;
    if (e < N_EDGES) {
        int pos = atomicAdd(&cursor[dst[e] * R_REL + et[e]], 1);
        srcS[pos] = src[e];
    }
}

// ---------------- converts ----------------

__global__ void k_cvt_x(const float* __restrict__ x, unsigned short* __restrict__ xb, int n4) {
    int i = blockIdx.x * 256 + threadIdx.x;
    if (i < n4) {
        float4 v = *(const float4*)(x + (size_t)i * 4);
        ushort4 o;
        o.x = f2bf(v.x); o.y = f2bf(v.y); o.z = f2bf(v.z); o.w = f2bf(v.w);
        *(ushort4*)(xb + (size_t)i * 4) = o;
    }
}

// Both layers' weights in one launch.
// Wt[seg][n][k] bf16, seg0 = root, segs 1..8 = W[r]. Input root[k][n], W[r][k][n].
#define W1_ELEMS (9 * 128 * 128)
#define W2_ELEMS (9 * 64 * 128)
__global__ void k_wprep_all(const float* __restrict__ root1, const float* __restrict__ W1,
                            const float* __restrict__ root2, const float* __restrict__ W2,
                            unsigned short* __restrict__ Wt1, unsigned short* __restrict__ Wt2) {
    int idx = blockIdx.x * 256 + threadIdx.x;
    if (idx < W1_ELEMS) {
        int k = idx & 127;
        int rest = idx >> 7;       // seg*128 + n
        int n = rest & 127;
        int seg = rest >> 7;
        float v = (seg == 0) ? root1[k * 128 + n] : W1[((seg - 1) * 128 + k) * 128 + n];
        Wt1[idx] = f2bf(v);
    } else if (idx < W1_ELEMS + W2_ELEMS) {
        int j = idx - W1_ELEMS;
        int k = j & 127;
        int rest = j >> 7;         // seg*64 + n
        int n = rest & 63;
        int seg = rest >> 6;
        float v = (seg == 0) ? root2[k * 64 + n] : W2[((seg - 1) * 128 + k) * 64 + n];
        Wt2[j] = f2bf(v);
    }
}

// ---------------- pure gather: mean-aggregate per (node,rel) ----------------
// Thread = (pair, 32-feat quarter). No LDS, no barriers, ~56 VGPR -> max waves/CU.
// Lanes 4i..4i+3 share a pair -> row reads/writes coalesce in 64B quarters.
// Grid: CPAIRS*4/256 = 3125 blocks exactly (no guards).

__global__ __launch_bounds__(256) void k_gather(
    const unsigned short* __restrict__ xin,  // [N,128] bf16 rows
    const int* __restrict__ offs,            // [NR+1]
    const int* __restrict__ srcS,            // [E]
    int pair0,                               // chunk start pair index
    unsigned short* __restrict__ agg)        // [CPAIRS][128] bf16
{
    const int tg = blockIdx.x * 256 + threadIdx.x;
    const int pl = tg >> 2;           // chunk-local pair
    const int q  = tg & 3;            // feature quarter
    const int pair = pair0 + pl;

    const int beg = offs[pair];
    const int end = offs[pair + 1];
    const int deg = end - beg;

    const unsigned short* bx = xin + q * 32;
    float a[32];
#pragma unroll
    for (int i = 0; i < 32; ++i) a[i] = 0.f;

    for (int j = beg; j < end; ++j) {
        int s = srcS[j];
        const uint4* p = (const uint4*)(bx + (size_t)s * 128);
        uint4 v0 = p[0], v1 = p[1], v2 = p[2], v3 = p[3];
        acc16(a, v0, v1);
        acc16(a + 16, v2, v3);
    }

    float scl = 1.f / (float)(deg > 1 ? deg : 1);
    unsigned int pk[16];
#pragma unroll
    for (int i = 0; i < 16; ++i)
        pk[i] = (unsigned int)f2bf(a[i * 2] * scl) |
                ((unsigned int)f2bf(a[i * 2 + 1] * scl) << 16);
    uint4* d = (uint4*)(agg + (size_t)pl * 128 + q * 32);
    d[0] = make_uint4(pk[0],  pk[1],  pk[2],  pk[3]);
    d[1] = make_uint4(pk[4],  pk[5],  pk[6],  pk[7]);
    d[2] = make_uint4(pk[8],  pk[9],  pk[10], pk[11]);
    d[3] = make_uint4(pk[12], pk[13], pk[14], pk[15]);
}

// ---------------- dense MFMA GEMM over 9 segments ----------------
// Block = 256 thr / 4 waves, M=32 node tile. K = 9 segs x 128.
// A staged in LDS, double-buffered, COALESCED loads (thread t: row t>>3,
// 32B slice t&7) -> no stragglers. B frags from global Wt (L2-resident).
// Wave w: row-half rh=w&1, col-half ch=w>>1 (NBW col-tiles each).
// 1 barrier per seg; prefetch of seg+1 overlaps MFMA of seg.

template <int FOUT, bool RELU, bool OUT_BF16>
__global__ __launch_bounds__(256) void k_gemm(
    const unsigned short* __restrict__ xin,  // [N,128] bf16 (seg 0 rows, global idx)
    const unsigned short* __restrict__ agg,  // [CPAIRS][128] bf16 (chunk-local)
    const unsigned short* __restrict__ Wt,   // [9][FOUT][128] bf16
    const float* __restrict__ bias,          // [FOUT]
    int n0, int ncount,                      // chunk node range
    unsigned short* __restrict__ outb,       // [N,FOUT] bf16 (if OUT_BF16)
    float* __restrict__ outf)                // [N,FOUT] fp32 (else)
{
    constexpr int NBW = FOUT / 32;           // col-tiles per wave: 4 (L1) / 2 (L2)
    __shared__ __align__(16) unsigned short As[2][32][136];

    const int t = threadIdx.x;
    const int nl0 = blockIdx.x * 32;         // chunk-local tile base
    // staging mapping
    const int sr = t >> 3;                   // local row 0..31
    const int sp = t & 7;                    // 32B slice (16 shorts)
    int srl = nl0 + sr;
    if (srl >= ncount) srl = ncount - 1;     // clamp (epilogue guards stores)
    const int gnode = n0 + srl;
    // mfma mapping
    const int lane = t & 63;
    const int w = t >> 6;
    const int quad = lane >> 4;
    const int tc = lane & 15;
    const int rh = w & 1;
    const int ch = w >> 1;

    f32x4 acc[NBW];
#pragma unroll
    for (int nb = 0; nb < NBW; ++nb) acc[nb] = (f32x4){0.f, 0.f, 0.f, 0.f};

    // stage seg 0 (root rows from xin)
    {
        const uint4* src = (const uint4*)(xin + (size_t)gnode * 128 + sp * 16);
        uint4 r0 = src[0], r1 = src[1];
        uint4* d = (uint4*)&As[0][sr][sp * 16];
        d[0] = r0; d[1] = r1;
    }
    __syncthreads();

    for (int seg = 0; seg < 9; ++seg) {
        const int buf = seg & 1;
        // prefetch next seg into regs (overlaps MFMA below)
        uint4 p0, p1;
        const bool pf = (seg < 8);
        if (pf) {
            const uint4* src = (const uint4*)(agg + ((size_t)srl * 8 + seg) * 128 + sp * 16);
            p0 = src[0]; p1 = src[1];
        }

        const unsigned short* Arow = &As[buf][rh * 16 + tc][0];
        const unsigned short* Bb = Wt + (size_t)seg * FOUT * 128 + quad * 8;
#pragma unroll
        for (int kk = 0; kk < 4; ++kk) {
            bf16x8 af = *(const bf16x8*)(Arow + kk * 32 + quad * 8);
#pragma unroll
            for (int nb = 0; nb < NBW; ++nb) {
                bf16x8 bf = *(const bf16x8*)(Bb + ((ch * NBW + nb) * 16 + tc) * 128 + kk * 32);
                acc[nb] = __builtin_amdgcn_mfma_f32_16x16x32_bf16(af, bf, acc[nb], 0, 0, 0);
            }
        }

        if (pf) {
            uint4* d = (uint4*)&As[buf ^ 1][sr][sp * 16];
            d[0] = p0; d[1] = p1;
        }
        __syncthreads();
    }

    // epilogue: D layout col = lane&15, row = quad*4 + reg
#pragma unroll
    for (int nb = 0; nb < NBW; ++nb) {
        int col = (ch * NBW + nb) * 16 + tc;
        float bs = bias[col];
#pragma unroll
        for (int i = 0; i < 4; ++i) {
            int rl = nl0 + rh * 16 + quad * 4 + i;
            if (rl < ncount) {
                int r = n0 + rl;
                float v = acc[nb][i] + bs;
                if (RELU) v = fmaxf(v, 0.f);
                if (OUT_BF16) outb[(size_t)r * FOUT + col] = f2bf(v);
                else          outf[(size_t)r * FOUT + col] = v;
            }
        }
    }
}

// ---------------- launch ----------------

extern "C" void kernel_launch(void* const* d_in, const int* in_sizes, int n_in,
                              void* d_out, int out_size, void* d_ws, size_t ws_size,
                              hipStream_t stream) {
    const float* x     = (const float*)d_in[0];
    const int*   ei    = (const int*)d_in[1];  // [2][E]: row0=src, row1=dst
    const int*   et    = (const int*)d_in[2];  // [E]
    const float* W1    = (const float*)d_in[3];
    const float* root1 = (const float*)d_in[4];
    const float* b1    = (const float*)d_in[5];
    const float* W2    = (const float*)d_in[6];
    const float* root2 = (const float*)d_in[7];
    const float* b2    = (const float*)d_in[8];
    float* out = (float*)d_out;

    int* ws     = (int*)d_ws;
    int* cnt    = ws;                  // NR  (reused for Wt1 after scans)
    int* offs   = cnt + NR;            // NR+1 (padded to NR+128)
    int* cursor = offs + NR + 128;     // NR  (reused for Wt2 after scatter)
    int* bsum   = cursor + NR;         // 256
    int* bsum2  = bsum + 256;          // 256
    int* srcS   = bsum2 + 256;         // E
    unsigned short* xb  = (unsigned short*)(srcS + N_EDGES); // [N,128] bf16 (12.8 MB)
    unsigned short* hb  = xb + (size_t)N_NODES * 128;        // [N,128] bf16 (12.8 MB)
    unsigned short* agg = hb + (size_t)N_NODES * 128;        // [CPAIRS,128] bf16 (51.2 MB)
    unsigned short* Wt1 = (unsigned short*)cnt;              // 288 KB < 1.6 MB
    unsigned short* Wt2 = (unsigned short*)cursor;           // 144 KB < 1.6 MB
    // total ws usage: 8.0 MB ints + 12.8 + 12.8 + 51.2 = 84.8 MB

    hipMemsetAsync(cnt, 0, NR * sizeof(int), stream);
    k_hist<<<(N_EDGES + 255) / 256, 256, 0, stream>>>(ei + N_EDGES, et, cnt);
    k_scan1<<<SCAN_NBLK, 256, 0, stream>>>(cnt, offs, bsum);
    k_scan2<<<1, 256, 0, stream>>>(bsum, bsum2);
    k_scan3<<<SCAN_NBLK, 256, 0, stream>>>(offs, bsum2, cursor);
    k_scatter<<<(N_EDGES + 255) / 256, 256, 0, stream>>>(ei, ei + N_EDGES, et, cursor, srcS);

    // cnt dead after k_scan1, cursor dead after k_scatter -> safe to overwrite now
    k_wprep_all<<<(W1_ELEMS + W2_ELEMS + 255) / 256, 256, 0, stream>>>(
        root1, W1, root2, W2, Wt1, Wt2);
    k_cvt_x<<<(N_NODES * 32 + 255) / 256, 256, 0, stream>>>(x, xb, N_NODES * 32);

    const int GB = (CPAIRS * 4) / 256;          // 3125 gather blocks (exact)
    const int MB = (NCHUNK + 31) / 32;          // 782 gemm blocks per chunk

    // layer 1 (chunked over nodes; agg reused per chunk)
    for (int c = 0; c < 2; ++c) {
        int n0 = c * NCHUNK;
        k_gather<<<GB, 256, 0, stream>>>(xb, offs, srcS, n0 * R_REL, agg);
        k_gemm<128, true, true><<<MB, 256, 0, stream>>>(
            xb, agg, Wt1, b1, n0, NCHUNK, hb, nullptr);
    }
    // layer 2 (hb fully written by both layer-1 chunks before first gather here)
    for (int c = 0; c < 2; ++c) {
        int n0 = c * NCHUNK;
        k_gather<<<GB, 256, 0, stream>>>(hb, offs, srcS, n0 * R_REL, agg);
        k_gemm<64, false, false><<<MB, 256, 0, stream>>>(
            hb, agg, Wt2, b2, n0, NCHUNK, nullptr, out);
    }
}

// Round 8
// 400.459 us; speedup vs baseline: 1.3153x; 1.3153x over previous
//
#include <hip/hip_runtime.h>

#define N_NODES 50000
#define N_EDGES 800000
#define R_REL   8
#define NR      (N_NODES * R_REL)        // 400000
#define SCAN_CHUNK 2048
#define SCAN_NBLK  ((NR + SCAN_CHUNK - 1) / SCAN_CHUNK)   // 196

#define NCHUNK  25000                    // nodes per chunk (2 chunks)
#define CPAIRS  (NCHUNK * R_REL)         // 200000 pairs per chunk

typedef float  f32x4  __attribute__((ext_vector_type(4)));
typedef __bf16 bf16x8 __attribute__((ext_vector_type(8)));

__device__ __forceinline__ unsigned short f2bf(float f) {
    unsigned int u = __float_as_uint(f);
    u = (u + 0x7FFFu + ((u >> 16) & 1u)) >> 16;   // RNE
    return (unsigned short)u;
}
__device__ __forceinline__ float bflo(unsigned int u) { return __uint_as_float(u << 16); }
__device__ __forceinline__ float bfhi(unsigned int u) { return __uint_as_float(u & 0xFFFF0000u); }

__device__ __forceinline__ void acc16(float* a, uint4 u0, uint4 u1) {
    a[0]  += bflo(u0.x);   a[1]  += bfhi(u0.x);
    a[2]  += bflo(u0.y);   a[3]  += bfhi(u0.y);
    a[4]  += bflo(u0.z);   a[5]  += bfhi(u0.z);
    a[6]  += bflo(u0.w);   a[7]  += bfhi(u0.w);
    a[8]  += bflo(u1.x);   a[9]  += bfhi(u1.x);
    a[10] += bflo(u1.y);   a[11] += bfhi(u1.y);
    a[12] += bflo(u1.z);   a[13] += bfhi(u1.z);
    a[14] += bflo(u1.w);   a[15] += bfhi(u1.w);
}

// ---------------- CSR build ----------------

__global__ void k_hist(const int* __restrict__ dst, const int* __restrict__ et,
                       int* __restrict__ cnt) {
    int e = blockIdx.x * 256 + threadIdx.x;
    if (e < N_EDGES) atomicAdd(&cnt[dst[e] * R_REL + et[e]], 1);
}

__global__ void k_scan1(const int* __restrict__ cnt, int* __restrict__ offs,
                        int* __restrict__ bsum) {
    __shared__ int sd[256];
    int t = threadIdx.x;
    int base = blockIdx.x * SCAN_CHUNK + t * 8;
    int v[8];
    int tot = 0;
#pragma unroll
    for (int i = 0; i < 8; i++) {
        int idx = base + i;
        int xv = (idx < NR) ? cnt[idx] : 0;
        v[i] = tot;
        tot += xv;
    }
    sd[t] = tot;
    __syncthreads();
    for (int off = 1; off < 256; off <<= 1) {
        int y = (t >= off) ? sd[t - off] : 0;
        __syncthreads();
        sd[t] += y;
        __syncthreads();
    }
    int excl = sd[t] - tot;
#pragma unroll
    for (int i = 0; i < 8; i++) {
        int idx = base + i;
        if (idx < NR) offs[idx] = v[i] + excl;
    }
    if (t == 255) bsum[blockIdx.x] = sd[255];
}

__global__ void k_scan2(const int* __restrict__ bsum, int* __restrict__ bsum2) {
    __shared__ int sd[256];
    int t = threadIdx.x;
    int v = (t < SCAN_NBLK) ? bsum[t] : 0;
    sd[t] = v;
    __syncthreads();
    for (int off = 1; off < 256; off <<= 1) {
        int y = (t >= off) ? sd[t - off] : 0;
        __syncthreads();
        sd[t] += y;
        __syncthreads();
    }
    bsum2[t] = sd[t] - v;
}

__global__ void k_scan3(int* __restrict__ offs, const int* __restrict__ bsum2,
                        int* __restrict__ cursor) {
    int t = threadIdx.x;
    int b = blockIdx.x;
    int add = bsum2[b];
    int base = b * SCAN_CHUNK + t * 8;
#pragma unroll
    for (int i = 0; i < 8; i++) {
        int idx = base + i;
        if (idx < NR) {
            int v = offs[idx] + add;
            offs[idx] = v;
            cursor[idx] = v;
        }
    }
    if (b == 0 && t == 0) offs[NR] = N_EDGES;
}

__global__ void k_scatter(const int* __restrict__ src, const int* __restrict__ dst,
                          const int* __restrict__ et, int* __restrict__ cursor,
                          int* __restrict__ srcS) {
    int e = blockIdx.x * 256 + threadIdx.x;
    if (e < N_EDGES) {
        int pos = atomicAdd(&cursor[dst[e] * R_REL + et[e]], 1);
        srcS[pos] = src[e];
    }
}

// ---------------- converts ----------------

__global__ void k_cvt_x(const float* __restrict__ x, unsigned short* __restrict__ xb, int n4) {
    int i = blockIdx.x * 256 + threadIdx.x;
    if (i < n4) {
        float4 v = *(const float4*)(x + (size_t)i * 4);
        ushort4 o;
        o.x = f2bf(v.x); o.y = f2bf(v.y); o.z = f2bf(v.z); o.w = f2bf(v.w);
        *(ushort4*)(xb + (size_t)i * 4) = o;
    }
}

// Fragment-ordered weight packing:
// WtP[(((seg*4 + kk)*NBt + nb)*64 + lane)*8 + j] = B[seg][n=nb*16+(lane&15)][k=kk*32+(lane>>4)*8+j]
// -> every B-fragment load is one coalesced 1-KB wave read.
#define W1_ELEMS (9 * 128 * 128)   // NBt=8
#define W2_ELEMS (9 * 64 * 128)    // NBt=4
__global__ void k_wprep_all(const float* __restrict__ root1, const float* __restrict__ W1,
                            const float* __restrict__ root2, const float* __restrict__ W2,
                            unsigned short* __restrict__ Wt1, unsigned short* __restrict__ Wt2) {
    int idx = blockIdx.x * 256 + threadIdx.x;
    if (idx < W1_ELEMS) {
        int j    = idx & 7;
        int lane = (idx >> 3) & 63;
        int r    = idx >> 9;
        int nb   = r & 7;        // NBt = 8
        int r2   = r >> 3;
        int kk   = r2 & 3;
        int seg  = r2 >> 2;
        int k = kk * 32 + (lane >> 4) * 8 + j;
        int n = nb * 16 + (lane & 15);
        float v = (seg == 0) ? root1[k * 128 + n] : W1[((seg - 1) * 128 + k) * 128 + n];
        Wt1[idx] = f2bf(v);
    } else if (idx < W1_ELEMS + W2_ELEMS) {
        int i2   = idx - W1_ELEMS;
        int j    = i2 & 7;
        int lane = (i2 >> 3) & 63;
        int r    = i2 >> 9;
        int nb   = r & 3;        // NBt = 4
        int r2   = r >> 2;
        int kk   = r2 & 3;
        int seg  = r2 >> 2;
        int k = kk * 32 + (lane >> 4) * 8 + j;
        int n = nb * 16 + (lane & 15);
        float v = (seg == 0) ? root2[k * 64 + n] : W2[((seg - 1) * 128 + k) * 64 + n];
        Wt2[i2] = f2bf(v);
    }
}

// ---------------- pure gather: mean-aggregate per (node,rel) ----------------
// Grid: (ceil(NCHUNK*4/256), 8); blockIdx.y = rel. Thread = (node, 32-feat quarter).
// No LDS, no barriers -> max waves/CU. agg layout [rel][node][128] so the GEMM's
// per-seg A-stage reads one contiguous 8-KB block.

__global__ __launch_bounds__(256) void k_gather(
    const unsigned short* __restrict__ xin,  // [N,128] bf16 rows
    const int* __restrict__ offs,            // [NR+1]
    const int* __restrict__ srcS,            // [E]
    int n0,                                  // chunk start node
    unsigned short* __restrict__ agg)        // [8][NCHUNK][128] bf16
{
    const int tg = blockIdx.x * 256 + threadIdx.x;
    const int node = tg >> 2;         // chunk-local node
    if (node >= NCHUNK) return;
    const int q   = tg & 3;           // feature quarter
    const int rel = blockIdx.y;

    const int pair = (n0 + node) * 8 + rel;
    const int beg = offs[pair];
    const int end = offs[pair + 1];
    const int deg = end - beg;

    const unsigned short* bx = xin + q * 32;
    float a[32];
#pragma unroll
    for (int i = 0; i < 32; ++i) a[i] = 0.f;

    for (int j = beg; j < end; ++j) {
        int s = srcS[j];
        const uint4* p = (const uint4*)(bx + (size_t)s * 128);
        uint4 v0 = p[0], v1 = p[1], v2 = p[2], v3 = p[3];
        acc16(a, v0, v1);
        acc16(a + 16, v2, v3);
    }

    float scl = 1.f / (float)(deg > 1 ? deg : 1);
    unsigned int pk[16];
#pragma unroll
    for (int i = 0; i < 16; ++i)
        pk[i] = (unsigned int)f2bf(a[i * 2] * scl) |
                ((unsigned int)f2bf(a[i * 2 + 1] * scl) << 16);
    uint4* d = (uint4*)(agg + ((size_t)rel * NCHUNK + node) * 128 + q * 32);
    d[0] = make_uint4(pk[0],  pk[1],  pk[2],  pk[3]);
    d[1] = make_uint4(pk[4],  pk[5],  pk[6],  pk[7]);
    d[2] = make_uint4(pk[8],  pk[9],  pk[10], pk[11]);
    d[3] = make_uint4(pk[12], pk[13], pk[14], pk[15]);
}

// ---------------- dense MFMA GEMM over 9 segments ----------------
// Block = 256 thr / 4 waves, M=32 node tile. K = 9 segs x 128.
// A staged in LDS (double-buffered, coalesced 8-KB per-seg block reads).
// B fragments from fragment-ordered WtP: one coalesced 1-KB wave load each.
// Wave w: row-half rh=w&1, col-half ch=w>>1 (NBW col-tiles each).

template <int FOUT, bool RELU, bool OUT_BF16>
__global__ __launch_bounds__(256) void k_gemm(
    const unsigned short* __restrict__ xin,  // [N,128] bf16 (seg 0 rows, global idx)
    const unsigned short* __restrict__ agg,  // [8][NCHUNK][128] bf16 (chunk-local)
    const unsigned short* __restrict__ WtP,  // fragment-ordered weights
    const float* __restrict__ bias,          // [FOUT]
    int n0, int ncount,                      // chunk node range
    unsigned short* __restrict__ outb,       // [N,FOUT] bf16 (if OUT_BF16)
    float* __restrict__ outf)                // [N,FOUT] fp32 (else)
{
    constexpr int NBt = FOUT / 16;           // total col tiles: 8 / 4
    constexpr int NBW = FOUT / 32;           // col-tiles per wave: 4 / 2
    __shared__ __align__(16) unsigned short As[2][32][136];

    const int t = threadIdx.x;
    const int nl0 = blockIdx.x * 32;         // chunk-local tile base
    // staging mapping
    const int sr = t >> 3;                   // local row 0..31
    const int sp = t & 7;                    // 32B slice (16 shorts)
    int srl = nl0 + sr;
    if (srl >= ncount) srl = ncount - 1;     // clamp (epilogue guards stores)
    const int gnode = n0 + srl;
    // mfma mapping
    const int lane = t & 63;
    const int w = t >> 6;
    const int quad = lane >> 4;
    const int tc = lane & 15;
    const int rh = w & 1;
    const int ch = w >> 1;

    f32x4 acc[NBW];
#pragma unroll
    for (int nb = 0; nb < NBW; ++nb) acc[nb] = (f32x4){0.f, 0.f, 0.f, 0.f};

    // stage seg 0 (root rows from xin)
    {
        const uint4* src = (const uint4*)(xin + (size_t)gnode * 128 + sp * 16);
        uint4 r0 = src[0], r1 = src[1];
        uint4* d = (uint4*)&As[0][sr][sp * 16];
        d[0] = r0; d[1] = r1;
    }
    __syncthreads();

    const bf16x8* Bp = (const bf16x8*)WtP;

    for (int seg = 0; seg < 9; ++seg) {
        const int buf = seg & 1;
        // prefetch next seg's A rows (rel = seg) into regs (overlaps MFMA below)
        uint4 p0, p1;
        const bool pf = (seg < 8);
        if (pf) {
            const uint4* src = (const uint4*)(agg + ((size_t)seg * NCHUNK + srl) * 128 + sp * 16);
            p0 = src[0]; p1 = src[1];
        }

        const unsigned short* Arow = &As[buf][rh * 16 + tc][0];
#pragma unroll
        for (int kk = 0; kk < 4; ++kk) {
            bf16x8 af = *(const bf16x8*)(Arow + kk * 32 + quad * 8);
#pragma unroll
            for (int nb = 0; nb < NBW; ++nb) {
                bf16x8 bf = Bp[((seg * 4 + kk) * NBt + ch * NBW + nb) * 64 + lane];
                acc[nb] = __builtin_amdgcn_mfma_f32_16x16x32_bf16(af, bf, acc[nb], 0, 0, 0);
            }
        }

        if (pf) {
            uint4* d = (uint4*)&As[buf ^ 1][sr][sp * 16];
            d[0] = p0; d[1] = p1;
        }
        __syncthreads();
    }

    // epilogue: D layout col = lane&15, row = quad*4 + reg
#pragma unroll
    for (int nb = 0; nb < NBW; ++nb) {
        int col = (ch * NBW + nb) * 16 + tc;
        float bs = bias[col];
#pragma unroll
        for (int i = 0; i < 4; ++i) {
            int rl = nl0 + rh * 16 + quad * 4 + i;
            if (rl < ncount) {
                int r = n0 + rl;
                float v = acc[nb][i] + bs;
                if (RELU) v = fmaxf(v, 0.f);
                if (OUT_BF16) outb[(size_t)r * FOUT + col] = f2bf(v);
                else          outf[(size_t)r * FOUT + col] = v;
            }
        }
    }
}

// ---------------- launch ----------------

extern "C" void kernel_launch(void* const* d_in, const int* in_sizes, int n_in,
                              void* d_out, int out_size, void* d_ws, size_t ws_size,
                              hipStream_t stream) {
    const float* x     = (const float*)d_in[0];
    const int*   ei    = (const int*)d_in[1];  // [2][E]: row0=src, row1=dst
    const int*   et    = (const int*)d_in[2];  // [E]
    const float* W1    = (const float*)d_in[3];
    const float* root1 = (const float*)d_in[4];
    const float* b1    = (const float*)d_in[5];
    const float* W2    = (const float*)d_in[6];
    const float* root2 = (const float*)d_in[7];
    const float* b2    = (const float*)d_in[8];
    float* out = (float*)d_out;

    int* ws     = (int*)d_ws;
    int* cnt    = ws;                  // NR  (reused for Wt1 after scans)
    int* offs   = cnt + NR;            // NR+1 (padded to NR+128)
    int* cursor = offs + NR + 128;     // NR  (reused for Wt2 after scatter)
    int* bsum   = cursor + NR;         // 256
    int* bsum2  = bsum + 256;          // 256
    int* srcS   = bsum2 + 256;         // E
    unsigned short* xb  = (unsigned short*)(srcS + N_EDGES); // [N,128] bf16 (12.8 MB)
    unsigned short* hb  = xb + (size_t)N_NODES * 128;        // [N,128] bf16 (12.8 MB)
    unsigned short* agg = hb + (size_t)N_NODES * 128;        // [8][NCHUNK][128] bf16 (51.2 MB)
    unsigned short* Wt1 = (unsigned short*)cnt;              // 288 KB < 1.6 MB
    unsigned short* Wt2 = (unsigned short*)cursor;           // 144 KB < 1.6 MB
    // total ws usage: 8.0 MB ints + 12.8 + 12.8 + 51.2 = 84.8 MB

    hipMemsetAsync(cnt, 0, NR * sizeof(int), stream);
    k_hist<<<(N_EDGES + 255) / 256, 256, 0, stream>>>(ei + N_EDGES, et, cnt);
    k_scan1<<<SCAN_NBLK, 256, 0, stream>>>(cnt, offs, bsum);
    k_scan2<<<1, 256, 0, stream>>>(bsum, bsum2);
    k_scan3<<<SCAN_NBLK, 256, 0, stream>>>(offs, bsum2, cursor);
    k_scatter<<<(N_EDGES + 255) / 256, 256, 0, stream>>>(ei, ei + N_EDGES, et, cursor, srcS);

    // cnt dead after k_scan1, cursor dead after k_scatter -> safe to overwrite now
    k_wprep_all<<<(W1_ELEMS + W2_ELEMS + 255) / 256, 256, 0, stream>>>(
        root1, W1, root2, W2, Wt1, Wt2);
    k_cvt_x<<<(N_NODES * 32 + 255) / 256, 256, 0, stream>>>(x, xb, N_NODES * 32);

    const dim3 GG((NCHUNK * 4 + 255) / 256, R_REL);  // (391, 8)
    const int MB = (NCHUNK + 31) / 32;               // 782 gemm blocks per chunk

    // layer 1 (chunked over nodes; agg reused per chunk)
    for (int c = 0; c < 2; ++c) {
        int n0 = c * NCHUNK;
        k_gather<<<GG, 256, 0, stream>>>(xb, offs, srcS, n0, agg);
        k_gemm<128, true, true><<<MB, 256, 0, stream>>>(
            xb, agg, Wt1, b1, n0, NCHUNK, hb, nullptr);
    }
    // layer 2 (hb fully written by both layer-1 chunks before first gather here)
    for (int c = 0; c < 2; ++c) {
        int n0 = c * NCHUNK;
        k_gather<<<GG, 256, 0, stream>>>(hb, offs, srcS, n0, agg);
        k_gemm<64, false, false><<<MB, 256, 0, stream>>>(
            hb, agg, Wt2, b2, n0, NCHUNK, nullptr, out);
    }
}

// Round 9
// 351.201 us; speedup vs baseline: 1.4998x; 1.1403x over previous
//
#include <hip/hip_runtime.h>

#define N_NODES 50000
#define N_EDGES 800000
#define R_REL   8
#define NR      (N_NODES * R_REL)        // 400000
#define SCAN_CHUNK 2048
#define SCAN_NBLK  ((NR + SCAN_CHUNK - 1) / SCAN_CHUNK)   // 196

#define NCHUNK  25000                    // nodes per chunk (2 chunks)

// bucketed CSR build
#define NBKT    196                      // buckets of 256 dst-nodes
#define BNSH    8                        // dst>>8 -> bucket
#define BKEYS   2048                     // keys per bucket (256 nodes x 8 rels)
#define BCAP    5120                     // record capacity per bucket (mean 4083, +16 sigma)
#define SLAB    2048                     // edges per bin-block
#define BINBLK  ((N_EDGES + SLAB - 1) / SLAB)  // 391

typedef float  f32x4  __attribute__((ext_vector_type(4)));
typedef __bf16 bf16x8 __attribute__((ext_vector_type(8)));

__device__ __forceinline__ unsigned short f2bf(float f) {
    unsigned int u = __float_as_uint(f);
    u = (u + 0x7FFFu + ((u >> 16) & 1u)) >> 16;   // RNE
    return (unsigned short)u;
}
__device__ __forceinline__ float bflo(unsigned int u) { return __uint_as_float(u << 16); }
__device__ __forceinline__ float bfhi(unsigned int u) { return __uint_as_float(u & 0xFFFF0000u); }

__device__ __forceinline__ void acc16(float* a, uint4 u0, uint4 u1) {
    a[0]  += bflo(u0.x);   a[1]  += bfhi(u0.x);
    a[2]  += bflo(u0.y);   a[3]  += bfhi(u0.y);
    a[4]  += bflo(u0.z);   a[5]  += bfhi(u0.z);
    a[6]  += bflo(u0.w);   a[7]  += bfhi(u0.w);
    a[8]  += bflo(u1.x);   a[9]  += bfhi(u1.x);
    a[10] += bflo(u1.y);   a[11] += bfhi(u1.y);
    a[12] += bflo(u1.z);   a[13] += bfhi(u1.z);
    a[14] += bflo(u1.w);   a[15] += bfhi(u1.w);
}

// ---------------- bucketed CSR build ----------------

// Pass A: bin edges into per-bucket record streams. Few global atomics
// (per-block per-bucket reservation), dense-ish 8-B record writes.
__global__ __launch_bounds__(256) void k_binA(
    const int* __restrict__ src, const int* __restrict__ dst,
    const int* __restrict__ et, int* __restrict__ gcur,
    uint2* __restrict__ gbin)
{
    __shared__ int hist[NBKT];
    __shared__ int base[NBKT];
    const int t = threadIdx.x;
    const int e0 = blockIdx.x * SLAB;
    for (int i = t; i < NBKT; i += 256) hist[i] = 0;
    __syncthreads();
#pragma unroll
    for (int i = 0; i < SLAB / 256; ++i) {
        int e = e0 + i * 256 + t;
        if (e < N_EDGES) atomicAdd(&hist[dst[e] >> BNSH], 1);
    }
    __syncthreads();
    for (int i = t; i < NBKT; i += 256) {
        int h = hist[i];
        base[i] = (h > 0) ? atomicAdd(&gcur[i], h) : 0;
        hist[i] = 0;   // reuse as sub-cursor
    }
    __syncthreads();
#pragma unroll
    for (int i = 0; i < SLAB / 256; ++i) {
        int e = e0 + i * 256 + t;
        if (e < N_EDGES) {
            int d = dst[e];
            int b = d >> BNSH;
            int sub = atomicAdd(&hist[b], 1);
            gbin[b * BCAP + base[b] + sub] =
                make_uint2((unsigned)src[e], (unsigned)(d * 8 + et[e]));
        }
    }
}

// Pass B: per-bucket LDS key histogram -> dense cnt writes (covers every key,
// zeros included -> no memset of cnt, no 800k random global atomics).
__global__ __launch_bounds__(256) void k_bcount(
    const int* __restrict__ gcur, const uint2* __restrict__ gbin,
    int* __restrict__ cnt)
{
    __shared__ int lc[BKEYS];
    const int t = threadIdx.x;
    const int b = blockIdx.x;
    for (int i = t; i < BKEYS; i += 256) lc[i] = 0;
    __syncthreads();
    const int n = gcur[b];
    const uint2* rec = gbin + (size_t)b * BCAP;
    const int kbase = b * BKEYS;
    for (int j = t; j < n; j += 256)
        atomicAdd(&lc[rec[j].y - kbase], 1);
    __syncthreads();
    for (int i = t; i < BKEYS; i += 256) {
        int k = kbase + i;
        if (k < NR) cnt[k] = lc[i];
    }
}

// Pass C: per-bucket scatter. srcS writes land in one contiguous ~16 KB
// window per block -> dense writebacks (vs 51 MB of partial lines before).
__global__ __launch_bounds__(256) void k_bscat(
    const int* __restrict__ gcur, const uint2* __restrict__ gbin,
    const int* __restrict__ offs, int* __restrict__ srcS)
{
    __shared__ int cur[BKEYS];
    const int t = threadIdx.x;
    const int b = blockIdx.x;
    for (int i = t; i < BKEYS; i += 256) cur[i] = 0;
    __syncthreads();
    const int n = gcur[b];
    const uint2* rec = gbin + (size_t)b * BCAP;
    const int kbase = b * BKEYS;
    for (int j = t; j < n; j += 256) {
        uint2 r = rec[j];
        int sub = atomicAdd(&cur[r.y - kbase], 1);
        srcS[offs[r.y] + sub] = (int)r.x;
    }
}

// ---------------- scans (exclusive prefix over cnt) ----------------

__global__ void k_scan1(const int* __restrict__ cnt, int* __restrict__ offs,
                        int* __restrict__ bsum) {
    __shared__ int sd[256];
    int t = threadIdx.x;
    int base = blockIdx.x * SCAN_CHUNK + t * 8;
    int v[8];
    int tot = 0;
#pragma unroll
    for (int i = 0; i < 8; i++) {
        int idx = base + i;
        int xv = (idx < NR) ? cnt[idx] : 0;
        v[i] = tot;
        tot += xv;
    }
    sd[t] = tot;
    __syncthreads();
    for (int off = 1; off < 256; off <<= 1) {
        int y = (t >= off) ? sd[t - off] : 0;
        __syncthreads();
        sd[t] += y;
        __syncthreads();
    }
    int excl = sd[t] - tot;
#pragma unroll
    for (int i = 0; i < 8; i++) {
        int idx = base + i;
        if (idx < NR) offs[idx] = v[i] + excl;
    }
    if (t == 255) bsum[blockIdx.x] = sd[255];
}

__global__ void k_scan2(const int* __restrict__ bsum, int* __restrict__ bsum2) {
    __shared__ int sd[256];
    int t = threadIdx.x;
    int v = (t < SCAN_NBLK) ? bsum[t] : 0;
    sd[t] = v;
    __syncthreads();
    for (int off = 1; off < 256; off <<= 1) {
        int y = (t >= off) ? sd[t - off] : 0;
        __syncthreads();
        sd[t] += y;
        __syncthreads();
    }
    bsum2[t] = sd[t] - v;
}

__global__ void k_scan3(int* __restrict__ offs, const int* __restrict__ bsum2) {
    int t = threadIdx.x;
    int b = blockIdx.x;
    int add = bsum2[b];
    int base = b * SCAN_CHUNK + t * 8;
#pragma unroll
    for (int i = 0; i < 8; i++) {
        int idx = base + i;
        if (idx < NR) offs[idx] += add;
    }
    if (b == 0 && t == 0) offs[NR] = N_EDGES;
}

// ---------------- converts ----------------

__global__ void k_cvt_x(const float* __restrict__ x, unsigned short* __restrict__ xb, int n4) {
    int i = blockIdx.x * 256 + threadIdx.x;
    if (i < n4) {
        float4 v = *(const float4*)(x + (size_t)i * 4);
        ushort4 o;
        o.x = f2bf(v.x); o.y = f2bf(v.y); o.z = f2bf(v.z); o.w = f2bf(v.w);
        *(ushort4*)(xb + (size_t)i * 4) = o;
    }
}

// Fragment-ordered weight packing:
// WtP[(((seg*4 + kk)*NBt + nb)*64 + lane)*8 + j] = B[seg][n=nb*16+(lane&15)][k=kk*32+(lane>>4)*8+j]
// -> every B-fragment load is one coalesced 1-KB wave read.
#define W1_ELEMS (9 * 128 * 128)   // NBt=8
#define W2_ELEMS (9 * 64 * 128)    // NBt=4
__global__ void k_wprep_all(const float* __restrict__ root1, const float* __restrict__ W1,
                            const float* __restrict__ root2, const float* __restrict__ W2,
                            unsigned short* __restrict__ Wt1, unsigned short* __restrict__ Wt2) {
    int idx = blockIdx.x * 256 + threadIdx.x;
    if (idx < W1_ELEMS) {
        int j    = idx & 7;
        int lane = (idx >> 3) & 63;
        int r    = idx >> 9;
        int nb   = r & 7;        // NBt = 8
        int r2   = r >> 3;
        int kk   = r2 & 3;
        int seg  = r2 >> 2;
        int k = kk * 32 + (lane >> 4) * 8 + j;
        int n = nb * 16 + (lane & 15);
        float v = (seg == 0) ? root1[k * 128 + n] : W1[((seg - 1) * 128 + k) * 128 + n];
        Wt1[idx] = f2bf(v);
    } else if (idx < W1_ELEMS + W2_ELEMS) {
        int i2   = idx - W1_ELEMS;
        int j    = i2 & 7;
        int lane = (i2 >> 3) & 63;
        int r    = i2 >> 9;
        int nb   = r & 3;        // NBt = 4
        int r2   = r >> 2;
        int kk   = r2 & 3;
        int seg  = r2 >> 2;
        int k = kk * 32 + (lane >> 4) * 8 + j;
        int n = nb * 16 + (lane & 15);
        float v = (seg == 0) ? root2[k * 64 + n] : W2[((seg - 1) * 128 + k) * 64 + n];
        Wt2[i2] = f2bf(v);
    }
}

// ---------------- pure gather: mean-aggregate per (node,rel) ----------------
// Grid: (ceil(NCHUNK*4/256), 8); blockIdx.y = rel. Thread = (node, 32-feat quarter).
// No LDS, no barriers -> max waves/CU. agg layout [rel][node][128].

__global__ __launch_bounds__(256) void k_gather(
    const unsigned short* __restrict__ xin,  // [N,128] bf16 rows
    const int* __restrict__ offs,            // [NR+1]
    const int* __restrict__ srcS,            // [E]
    int n0,                                  // chunk start node
    unsigned short* __restrict__ agg)        // [8][NCHUNK][128] bf16
{
    const int tg = blockIdx.x * 256 + threadIdx.x;
    const int node = tg >> 2;         // chunk-local node
    if (node >= NCHUNK) return;
    const int q   = tg & 3;           // feature quarter
    const int rel = blockIdx.y;

    const int pair = (n0 + node) * 8 + rel;
    const int beg = offs[pair];
    const int end = offs[pair + 1];
    const int deg = end - beg;

    const unsigned short* bx = xin + q * 32;
    float a[32];
#pragma unroll
    for (int i = 0; i < 32; ++i) a[i] = 0.f;

    for (int j = beg; j < end; ++j) {
        int s = srcS[j];
        const uint4* p = (const uint4*)(bx + (size_t)s * 128);
        uint4 v0 = p[0], v1 = p[1], v2 = p[2], v3 = p[3];
        acc16(a, v0, v1);
        acc16(a + 16, v2, v3);
    }

    float scl = 1.f / (float)(deg > 1 ? deg : 1);
    unsigned int pk[16];
#pragma unroll
    for (int i = 0; i < 16; ++i)
        pk[i] = (unsigned int)f2bf(a[i * 2] * scl) |
                ((unsigned int)f2bf(a[i * 2 + 1] * scl) << 16);
    uint4* d = (uint4*)(agg + ((size_t)rel * NCHUNK + node) * 128 + q * 32);
    d[0] = make_uint4(pk[0],  pk[1],  pk[2],  pk[3]);
    d[1] = make_uint4(pk[4],  pk[5],  pk[6],  pk[7]);
    d[2] = make_uint4(pk[8],  pk[9],  pk[10], pk[11]);
    d[3] = make_uint4(pk[12], pk[13], pk[14], pk[15]);
}

// ---------------- dense MFMA GEMM over 9 segments ----------------
// Block = 256 thr / 4 waves, M=32 node tile. K = 9 segs x 128.
// A staged in LDS (double-buffered, coalesced per-seg block reads).
// B fragments from fragment-ordered WtP: one coalesced 1-KB wave load each.

template <int FOUT, bool RELU, bool OUT_BF16>
__global__ __launch_bounds__(256) void k_gemm(
    const unsigned short* __restrict__ xin,  // [N,128] bf16 (seg 0 rows, global idx)
    const unsigned short* __restrict__ agg,  // [8][NCHUNK][128] bf16 (chunk-local)
    const unsigned short* __restrict__ WtP,  // fragment-ordered weights
    const float* __restrict__ bias,          // [FOUT]
    int n0, int ncount,                      // chunk node range
    unsigned short* __restrict__ outb,       // [N,FOUT] bf16 (if OUT_BF16)
    float* __restrict__ outf)                // [N,FOUT] fp32 (else)
{
    constexpr int NBt = FOUT / 16;           // total col tiles: 8 / 4
    constexpr int NBW = FOUT / 32;           // col-tiles per wave: 4 / 2
    __shared__ __align__(16) unsigned short As[2][32][136];

    const int t = threadIdx.x;
    const int nl0 = blockIdx.x * 32;         // chunk-local tile base
    const int sr = t >> 3;                   // local row 0..31
    const int sp = t & 7;                    // 32B slice (16 shorts)
    int srl = nl0 + sr;
    if (srl >= ncount) srl = ncount - 1;     // clamp (epilogue guards stores)
    const int gnode = n0 + srl;
    const int lane = t & 63;
    const int w = t >> 6;
    const int quad = lane >> 4;
    const int tc = lane & 15;
    const int rh = w & 1;
    const int ch = w >> 1;

    f32x4 acc[NBW];
#pragma unroll
    for (int nb = 0; nb < NBW; ++nb) acc[nb] = (f32x4){0.f, 0.f, 0.f, 0.f};

    // stage seg 0 (root rows from xin)
    {
        const uint4* src = (const uint4*)(xin + (size_t)gnode * 128 + sp * 16);
        uint4 r0 = src[0], r1 = src[1];
        uint4* d = (uint4*)&As[0][sr][sp * 16];
        d[0] = r0; d[1] = r1;
    }
    __syncthreads();

    const bf16x8* Bp = (const bf16x8*)WtP;

    for (int seg = 0; seg < 9; ++seg) {
        const int buf = seg & 1;
        uint4 p0, p1;
        const bool pf = (seg < 8);
        if (pf) {
            const uint4* src = (const uint4*)(agg + ((size_t)seg * NCHUNK + srl) * 128 + sp * 16);
            p0 = src[0]; p1 = src[1];
        }

        const unsigned short* Arow = &As[buf][rh * 16 + tc][0];
#pragma unroll
        for (int kk = 0; kk < 4; ++kk) {
            bf16x8 af = *(const bf16x8*)(Arow + kk * 32 + quad * 8);
#pragma unroll
            for (int nb = 0; nb < NBW; ++nb) {
                bf16x8 bf = Bp[((seg * 4 + kk) * NBt + ch * NBW + nb) * 64 + lane];
                acc[nb] = __builtin_amdgcn_mfma_f32_16x16x32_bf16(af, bf, acc[nb], 0, 0, 0);
            }
        }

        if (pf) {
            uint4* d = (uint4*)&As[buf ^ 1][sr][sp * 16];
            d[0] = p0; d[1] = p1;
        }
        __syncthreads();
    }

    // epilogue: D layout col = lane&15, row = quad*4 + reg
#pragma unroll
    for (int nb = 0; nb < NBW; ++nb) {
        int col = (ch * NBW + nb) * 16 + tc;
        float bs = bias[col];
#pragma unroll
        for (int i = 0; i < 4; ++i) {
            int rl = nl0 + rh * 16 + quad * 4 + i;
            if (rl < ncount) {
                int r = n0 + rl;
                float v = acc[nb][i] + bs;
                if (RELU) v = fmaxf(v, 0.f);
                if (OUT_BF16) outb[(size_t)r * FOUT + col] = f2bf(v);
                else          outf[(size_t)r * FOUT + col] = v;
            }
        }
    }
}

// ---------------- launch ----------------

extern "C" void kernel_launch(void* const* d_in, const int* in_sizes, int n_in,
                              void* d_out, int out_size, void* d_ws, size_t ws_size,
                              hipStream_t stream) {
    const float* x     = (const float*)d_in[0];
    const int*   ei    = (const int*)d_in[1];  // [2][E]: row0=src, row1=dst
    const int*   et    = (const int*)d_in[2];  // [E]
    const float* W1    = (const float*)d_in[3];
    const float* root1 = (const float*)d_in[4];
    const float* b1    = (const float*)d_in[5];
    const float* W2    = (const float*)d_in[6];
    const float* root2 = (const float*)d_in[7];
    const float* b2    = (const float*)d_in[8];
    float* out = (float*)d_out;

    int* ws     = (int*)d_ws;
    int* cnt    = ws;                  // NR        (reused for Wt1 after scan1)
    int* offs   = cnt + NR;            // NR+128
    int* wt2buf = offs + NR + 128;     // NR        (holds Wt2, 144 KB)
    int* bsum   = wt2buf + NR;         // 256
    int* bsum2  = bsum + 256;          // 256
    int* gcur   = bsum2 + 256;         // 256
    int* srcS   = gcur + 256;          // E
    unsigned short* xb  = (unsigned short*)(srcS + N_EDGES); // [N,128] bf16 (12.8 MB)
    unsigned short* hb  = xb + (size_t)N_NODES * 128;        // [N,128] bf16 (12.8 MB)
    unsigned short* agg = hb + (size_t)N_NODES * 128;        // [8][NCHUNK][128] bf16 (51.2 MB)
    uint2* gbin = (uint2*)agg;         // 196*5120*8 B = 8.03 MB, dead before first gather
    unsigned short* Wt1 = (unsigned short*)cnt;
    unsigned short* Wt2 = (unsigned short*)wt2buf;
    // total ws usage: ~14.4 MB ints + 12.8 + 12.8 + 51.2 = ~84.9 MB

    hipMemsetAsync(gcur, 0, 256 * sizeof(int), stream);
    k_binA<<<BINBLK, 256, 0, stream>>>(ei, ei + N_EDGES, et, gcur, gbin);
    k_bcount<<<NBKT, 256, 0, stream>>>(gcur, gbin, cnt);
    k_scan1<<<SCAN_NBLK, 256, 0, stream>>>(cnt, offs, bsum);
    k_scan2<<<1, 256, 0, stream>>>(bsum, bsum2);
    k_scan3<<<SCAN_NBLK, 256, 0, stream>>>(offs, bsum2);
    k_bscat<<<NBKT, 256, 0, stream>>>(gcur, gbin, offs, srcS);

    // cnt dead after scan1 -> Wt1 overwrites; wt2buf never aliased
    k_wprep_all<<<(W1_ELEMS + W2_ELEMS + 255) / 256, 256, 0, stream>>>(
        root1, W1, root2, W2, Wt1, Wt2);
    k_cvt_x<<<(N_NODES * 32 + 255) / 256, 256, 0, stream>>>(x, xb, N_NODES * 32);

    const dim3 GG((NCHUNK * 4 + 255) / 256, R_REL);  // (391, 8)
    const int MB = (NCHUNK + 31) / 32;               // 782 gemm blocks per chunk

    // layer 1 (chunked over nodes; agg reused per chunk; gbin dead by now)
    for (int c = 0; c < 2; ++c) {
        int n0 = c * NCHUNK;
        k_gather<<<GG, 256, 0, stream>>>(xb, offs, srcS, n0, agg);
        k_gemm<128, true, true><<<MB, 256, 0, stream>>>(
            xb, agg, Wt1, b1, n0, NCHUNK, hb, nullptr);
    }
    // layer 2 (hb fully written by both layer-1 chunks before first gather here)
    for (int c = 0; c < 2; ++c) {
        int n0 = c * NCHUNK;
        k_gather<<<GG, 256, 0, stream>>>(hb, offs, srcS, n0, agg);
        k_gemm<64, false, false><<<MB, 256, 0, stream>>>(
            hb, agg, Wt2, b2, n0, NCHUNK, nullptr, out);
    }
}

// Round 10
// 310.156 us; speedup vs baseline: 1.6982x; 1.1323x over previous
//
#include <hip/hip_runtime.h>

#define N_NODES 50000
#define N_EDGES 800000
#define R_REL   8
#define NR      (N_NODES * R_REL)        // 400000
#define SCAN_CHUNK 2048
#define SCAN_NBLK  ((NR + SCAN_CHUNK - 1) / SCAN_CHUNK)   // 196

#define NCHUNK  50000                    // single chunk (ws holds full agg)

// bucketed CSR build
#define NBKT    196                      // buckets of 256 dst-nodes
#define BNSH    8                        // dst>>8 -> bucket
#define BKEYS   2048                     // keys per bucket (256 nodes x 8 rels)
#define BCAP    5120                     // record capacity per bucket (mean 4083, +16 sigma)
#define SLAB    2048                     // edges per bin-block
#define BINBLK  ((N_EDGES + SLAB - 1) / SLAB)  // 391

typedef float  f32x4  __attribute__((ext_vector_type(4)));
typedef __bf16 bf16x8 __attribute__((ext_vector_type(8)));

__device__ __forceinline__ unsigned short f2bf(float f) {
    unsigned int u = __float_as_uint(f);
    u = (u + 0x7FFFu + ((u >> 16) & 1u)) >> 16;   // RNE
    return (unsigned short)u;
}
__device__ __forceinline__ float bflo(unsigned int u) { return __uint_as_float(u << 16); }
__device__ __forceinline__ float bfhi(unsigned int u) { return __uint_as_float(u & 0xFFFF0000u); }

__device__ __forceinline__ void acc16(float* a, uint4 u0, uint4 u1) {
    a[0]  += bflo(u0.x);   a[1]  += bfhi(u0.x);
    a[2]  += bflo(u0.y);   a[3]  += bfhi(u0.y);
    a[4]  += bflo(u0.z);   a[5]  += bfhi(u0.z);
    a[6]  += bflo(u0.w);   a[7]  += bfhi(u0.w);
    a[8]  += bflo(u1.x);   a[9]  += bfhi(u1.x);
    a[10] += bflo(u1.y);   a[11] += bfhi(u1.y);
    a[12] += bflo(u1.z);   a[13] += bfhi(u1.z);
    a[14] += bflo(u1.w);   a[15] += bfhi(u1.w);
}

// ---------------- bucketed CSR build ----------------

__global__ __launch_bounds__(256) void k_binA(
    const int* __restrict__ src, const int* __restrict__ dst,
    const int* __restrict__ et, int* __restrict__ gcur,
    uint2* __restrict__ gbin)
{
    __shared__ int hist[NBKT];
    __shared__ int base[NBKT];
    const int t = threadIdx.x;
    const int e0 = blockIdx.x * SLAB;
    for (int i = t; i < NBKT; i += 256) hist[i] = 0;
    __syncthreads();
#pragma unroll
    for (int i = 0; i < SLAB / 256; ++i) {
        int e = e0 + i * 256 + t;
        if (e < N_EDGES) atomicAdd(&hist[dst[e] >> BNSH], 1);
    }
    __syncthreads();
    for (int i = t; i < NBKT; i += 256) {
        int h = hist[i];
        base[i] = (h > 0) ? atomicAdd(&gcur[i], h) : 0;
        hist[i] = 0;   // reuse as sub-cursor
    }
    __syncthreads();
#pragma unroll
    for (int i = 0; i < SLAB / 256; ++i) {
        int e = e0 + i * 256 + t;
        if (e < N_EDGES) {
            int d = dst[e];
            int b = d >> BNSH;
            int sub = atomicAdd(&hist[b], 1);
            gbin[b * BCAP + base[b] + sub] =
                make_uint2((unsigned)src[e], (unsigned)(d * 8 + et[e]));
        }
    }
}

__global__ __launch_bounds__(256) void k_bcount(
    const int* __restrict__ gcur, const uint2* __restrict__ gbin,
    int* __restrict__ cnt)
{
    __shared__ int lc[BKEYS];
    const int t = threadIdx.x;
    const int b = blockIdx.x;
    for (int i = t; i < BKEYS; i += 256) lc[i] = 0;
    __syncthreads();
    const int n = gcur[b];
    const uint2* rec = gbin + (size_t)b * BCAP;
    const int kbase = b * BKEYS;
    for (int j = t; j < n; j += 256)
        atomicAdd(&lc[rec[j].y - kbase], 1);
    __syncthreads();
    for (int i = t; i < BKEYS; i += 256) {
        int k = kbase + i;
        if (k < NR) cnt[k] = lc[i];
    }
}

__global__ __launch_bounds__(256) void k_bscat(
    const int* __restrict__ gcur, const uint2* __restrict__ gbin,
    const int* __restrict__ offs, int* __restrict__ srcS)
{
    __shared__ int cur[BKEYS];
    const int t = threadIdx.x;
    const int b = blockIdx.x;
    for (int i = t; i < BKEYS; i += 256) cur[i] = 0;
    __syncthreads();
    const int n = gcur[b];
    const uint2* rec = gbin + (size_t)b * BCAP;
    const int kbase = b * BKEYS;
    for (int j = t; j < n; j += 256) {
        uint2 r = rec[j];
        int sub = atomicAdd(&cur[r.y - kbase], 1);
        srcS[offs[r.y] + sub] = (int)r.x;
    }
}

// ---------------- scans (exclusive prefix over cnt) ----------------

__global__ void k_scan1(const int* __restrict__ cnt, int* __restrict__ offs,
                        int* __restrict__ bsum) {
    __shared__ int sd[256];
    int t = threadIdx.x;
    int base = blockIdx.x * SCAN_CHUNK + t * 8;
    int v[8];
    int tot = 0;
#pragma unroll
    for (int i = 0; i < 8; i++) {
        int idx = base + i;
        int xv = (idx < NR) ? cnt[idx] : 0;
        v[i] = tot;
        tot += xv;
    }
    sd[t] = tot;
    __syncthreads();
    for (int off = 1; off < 256; off <<= 1) {
        int y = (t >= off) ? sd[t - off] : 0;
        __syncthreads();
        sd[t] += y;
        __syncthreads();
    }
    int excl = sd[t] - tot;
#pragma unroll
    for (int i = 0; i < 8; i++) {
        int idx = base + i;
        if (idx < NR) offs[idx] = v[i] + excl;
    }
    if (t == 255) bsum[blockIdx.x] = sd[255];
}

__global__ void k_scan2(const int* __restrict__ bsum, int* __restrict__ bsum2) {
    __shared__ int sd[256];
    int t = threadIdx.x;
    int v = (t < SCAN_NBLK) ? bsum[t] : 0;
    sd[t] = v;
    __syncthreads();
    for (int off = 1; off < 256; off <<= 1) {
        int y = (t >= off) ? sd[t - off] : 0;
        __syncthreads();
        sd[t] += y;
        __syncthreads();
    }
    bsum2[t] = sd[t] - v;
}

__global__ void k_scan3(int* __restrict__ offs, const int* __restrict__ bsum2) {
    int t = threadIdx.x;
    int b = blockIdx.x;
    int add = bsum2[b];
    int base = b * SCAN_CHUNK + t * 8;
#pragma unroll
    for (int i = 0; i < 8; i++) {
        int idx = base + i;
        if (idx < NR) offs[idx] += add;
    }
    if (b == 0 && t == 0) offs[NR] = N_EDGES;
}

// ---------------- converts ----------------

__global__ void k_cvt_x(const float* __restrict__ x, unsigned short* __restrict__ xb, int n4) {
    int i = blockIdx.x * 256 + threadIdx.x;
    if (i < n4) {
        float4 v = *(const float4*)(x + (size_t)i * 4);
        ushort4 o;
        o.x = f2bf(v.x); o.y = f2bf(v.y); o.z = f2bf(v.z); o.w = f2bf(v.w);
        *(ushort4*)(xb + (size_t)i * 4) = o;
    }
}

// Fragment-ordered weight packing:
// WtP[(((seg*4 + kk)*NBt + nb)*64 + lane)*8 + j] = B[seg][n=nb*16+(lane&15)][k=kk*32+(lane>>4)*8+j]
#define W1_ELEMS (9 * 128 * 128)   // NBt=8
#define W2_ELEMS (9 * 64 * 128)    // NBt=4
__global__ void k_wprep_all(const float* __restrict__ root1, const float* __restrict__ W1,
                            const float* __restrict__ root2, const float* __restrict__ W2,
                            unsigned short* __restrict__ Wt1, unsigned short* __restrict__ Wt2) {
    int idx = blockIdx.x * 256 + threadIdx.x;
    if (idx < W1_ELEMS) {
        int j    = idx & 7;
        int lane = (idx >> 3) & 63;
        int r    = idx >> 9;
        int nb   = r & 7;        // NBt = 8
        int r2   = r >> 3;
        int kk   = r2 & 3;
        int seg  = r2 >> 2;
        int k = kk * 32 + (lane >> 4) * 8 + j;
        int n = nb * 16 + (lane & 15);
        float v = (seg == 0) ? root1[k * 128 + n] : W1[((seg - 1) * 128 + k) * 128 + n];
        Wt1[idx] = f2bf(v);
    } else if (idx < W1_ELEMS + W2_ELEMS) {
        int i2   = idx - W1_ELEMS;
        int j    = i2 & 7;
        int lane = (i2 >> 3) & 63;
        int r    = i2 >> 9;
        int nb   = r & 3;        // NBt = 4
        int r2   = r >> 2;
        int kk   = r2 & 3;
        int seg  = r2 >> 2;
        int k = kk * 32 + (lane >> 4) * 8 + j;
        int n = nb * 16 + (lane & 15);
        float v = (seg == 0) ? root2[k * 64 + n] : W2[((seg - 1) * 128 + k) * 64 + n];
        Wt2[i2] = f2bf(v);
    }
}

// ---------------- pure gather: mean-aggregate per (node,rel) ----------------
// Grid: (782, 8); blockIdx.y = rel. Thread = (node, 32-feat quarter).
// No LDS, no barriers. 2-edge ILP: 8 independent dwordx4 per round to cut
// the wave round count (max deg over 16 pairs) ~5 -> ~3.

__global__ __launch_bounds__(256) void k_gather(
    const unsigned short* __restrict__ xin,  // [N,128] bf16 rows
    const int* __restrict__ offs,            // [NR+1]
    const int* __restrict__ srcS,            // [E]
    unsigned short* __restrict__ agg)        // [8][NCHUNK][128] bf16
{
    const int tg = blockIdx.x * 256 + threadIdx.x;
    const int node = tg >> 2;         // node
    if (node >= NCHUNK) return;
    const int q   = tg & 3;           // feature quarter
    const int rel = blockIdx.y;

    const int pair = node * 8 + rel;
    const int beg = offs[pair];
    const int end = offs[pair + 1];
    const int deg = end - beg;

    const unsigned short* bx = xin + q * 32;
    float a[32];
#pragma unroll
    for (int i = 0; i < 32; ++i) a[i] = 0.f;

    int j = beg;
    for (; j + 1 < end; j += 2) {
        int s0 = srcS[j];
        int s1 = srcS[j + 1];
        const uint4* p0 = (const uint4*)(bx + (size_t)s0 * 128);
        const uint4* p1 = (const uint4*)(bx + (size_t)s1 * 128);
        uint4 v0 = p0[0], v1 = p0[1], v2 = p0[2], v3 = p0[3];
        uint4 w0 = p1[0], w1 = p1[1], w2 = p1[2], w3 = p1[3];
        acc16(a, v0, v1);
        acc16(a + 16, v2, v3);
        acc16(a, w0, w1);
        acc16(a + 16, w2, w3);
    }
    if (j < end) {
        int s = srcS[j];
        const uint4* p = (const uint4*)(bx + (size_t)s * 128);
        uint4 v0 = p[0], v1 = p[1], v2 = p[2], v3 = p[3];
        acc16(a, v0, v1);
        acc16(a + 16, v2, v3);
    }

    float scl = 1.f / (float)(deg > 1 ? deg : 1);
    unsigned int pk[16];
#pragma unroll
    for (int i = 0; i < 16; ++i)
        pk[i] = (unsigned int)f2bf(a[i * 2] * scl) |
                ((unsigned int)f2bf(a[i * 2 + 1] * scl) << 16);
    uint4* d = (uint4*)(agg + ((size_t)rel * NCHUNK + node) * 128 + q * 32);
    d[0] = make_uint4(pk[0],  pk[1],  pk[2],  pk[3]);
    d[1] = make_uint4(pk[4],  pk[5],  pk[6],  pk[7]);
    d[2] = make_uint4(pk[8],  pk[9],  pk[10], pk[11]);
    d[3] = make_uint4(pk[12], pk[13], pk[14], pk[15]);
}

// ---------------- dense MFMA GEMM over 9 segments ----------------
// Block = 256 thr / 4 waves, M=32 node tile. K = 9 segs x 128.
// A staged in LDS (double-buffered, coalesced per-seg block reads).
// B fragments from fragment-ordered WtP: one coalesced 1-KB wave load each.

template <int FOUT, bool RELU, bool OUT_BF16>
__global__ __launch_bounds__(256) void k_gemm(
    const unsigned short* __restrict__ xin,  // [N,128] bf16 (seg 0 rows)
    const unsigned short* __restrict__ agg,  // [8][NCHUNK][128] bf16
    const unsigned short* __restrict__ WtP,  // fragment-ordered weights
    const float* __restrict__ bias,          // [FOUT]
    unsigned short* __restrict__ outb,       // [N,FOUT] bf16 (if OUT_BF16)
    float* __restrict__ outf)                // [N,FOUT] fp32 (else)
{
    constexpr int NBt = FOUT / 16;           // total col tiles: 8 / 4
    constexpr int NBW = FOUT / 32;           // col-tiles per wave: 4 / 2
    __shared__ __align__(16) unsigned short As[2][32][136];

    const int t = threadIdx.x;
    const int nl0 = blockIdx.x * 32;
    const int sr = t >> 3;                   // local row 0..31
    const int sp = t & 7;                    // 32B slice (16 shorts)
    int srl = nl0 + sr;
    if (srl >= NCHUNK) srl = NCHUNK - 1;     // clamp (epilogue guards stores)
    const int lane = t & 63;
    const int w = t >> 6;
    const int quad = lane >> 4;
    const int tc = lane & 15;
    const int rh = w & 1;
    const int ch = w >> 1;

    f32x4 acc[NBW];
#pragma unroll
    for (int nb = 0; nb < NBW; ++nb) acc[nb] = (f32x4){0.f, 0.f, 0.f, 0.f};

    // stage seg 0 (root rows from xin)
    {
        const uint4* src = (const uint4*)(xin + (size_t)srl * 128 + sp * 16);
        uint4 r0 = src[0], r1 = src[1];
        uint4* d = (uint4*)&As[0][sr][sp * 16];
        d[0] = r0; d[1] = r1;
    }
    __syncthreads();

    const bf16x8* Bp = (const bf16x8*)WtP;

    for (int seg = 0; seg < 9; ++seg) {
        const int buf = seg & 1;
        uint4 p0, p1;
        const bool pf = (seg < 8);
        if (pf) {
            const uint4* src = (const uint4*)(agg + ((size_t)seg * NCHUNK + srl) * 128 + sp * 16);
            p0 = src[0]; p1 = src[1];
        }

        const unsigned short* Arow = &As[buf][rh * 16 + tc][0];
#pragma unroll
        for (int kk = 0; kk < 4; ++kk) {
            bf16x8 af = *(const bf16x8*)(Arow + kk * 32 + quad * 8);
#pragma unroll
            for (int nb = 0; nb < NBW; ++nb) {
                bf16x8 bf = Bp[((seg * 4 + kk) * NBt + ch * NBW + nb) * 64 + lane];
                acc[nb] = __builtin_amdgcn_mfma_f32_16x16x32_bf16(af, bf, acc[nb], 0, 0, 0);
            }
        }

        if (pf) {
            uint4* d = (uint4*)&As[buf ^ 1][sr][sp * 16];
            d[0] = p0; d[1] = p1;
        }
        __syncthreads();
    }

    // epilogue: D layout col = lane&15, row = quad*4 + reg
#pragma unroll
    for (int nb = 0; nb < NBW; ++nb) {
        int col = (ch * NBW + nb) * 16 + tc;
        float bs = bias[col];
#pragma unroll
        for (int i = 0; i < 4; ++i) {
            int r = nl0 + rh * 16 + quad * 4 + i;
            if (r < NCHUNK) {
                float v = acc[nb][i] + bs;
                if (RELU) v = fmaxf(v, 0.f);
                if (OUT_BF16) outb[(size_t)r * FOUT + col] = f2bf(v);
                else          outf[(size_t)r * FOUT + col] = v;
            }
        }
    }
}

// ---------------- launch ----------------

extern "C" void kernel_launch(void* const* d_in, const int* in_sizes, int n_in,
                              void* d_out, int out_size, void* d_ws, size_t ws_size,
                              hipStream_t stream) {
    const float* x     = (const float*)d_in[0];
    const int*   ei    = (const int*)d_in[1];  // [2][E]: row0=src, row1=dst
    const int*   et    = (const int*)d_in[2];  // [E]
    const float* W1    = (const float*)d_in[3];
    const float* root1 = (const float*)d_in[4];
    const float* b1    = (const float*)d_in[5];
    const float* W2    = (const float*)d_in[6];
    const float* root2 = (const float*)d_in[7];
    const float* b2    = (const float*)d_in[8];
    float* out = (float*)d_out;

    int* ws     = (int*)d_ws;
    int* cnt    = ws;                  // NR        (reused for Wt1 after scan1)
    int* offs   = cnt + NR;            // NR+128
    int* wt2buf = offs + NR + 128;     // NR        (holds Wt2, 144 KB)
    int* bsum   = wt2buf + NR;         // 256
    int* bsum2  = bsum + 256;          // 256
    int* gcur   = bsum2 + 256;         // 256
    int* srcS   = gcur + 256;          // E
    unsigned short* xb  = (unsigned short*)(srcS + N_EDGES); // [N,128] bf16 (12.8 MB)
    unsigned short* hb  = xb + (size_t)N_NODES * 128;        // [N,128] bf16 (12.8 MB)
    unsigned short* agg = hb + (size_t)N_NODES * 128;        // [8][50000][128] bf16 (102.4 MB)
    uint2* gbin = (uint2*)agg;         // 8.03 MB, dead before first gather
    unsigned short* Wt1 = (unsigned short*)cnt;
    unsigned short* Wt2 = (unsigned short*)wt2buf;
    // total ws usage: ~8 MB ints + 12.8 + 12.8 + 102.4 = ~136 MB (ws = 256 MiB)

    hipMemsetAsync(gcur, 0, 256 * sizeof(int), stream);
    k_binA<<<BINBLK, 256, 0, stream>>>(ei, ei + N_EDGES, et, gcur, gbin);
    k_bcount<<<NBKT, 256, 0, stream>>>(gcur, gbin, cnt);
    k_scan1<<<SCAN_NBLK, 256, 0, stream>>>(cnt, offs, bsum);
    k_scan2<<<1, 256, 0, stream>>>(bsum, bsum2);
    k_scan3<<<SCAN_NBLK, 256, 0, stream>>>(offs, bsum2);
    k_bscat<<<NBKT, 256, 0, stream>>>(gcur, gbin, offs, srcS);

    // cnt dead after scan1 -> Wt1 overwrites; wt2buf never aliased
    k_wprep_all<<<(W1_ELEMS + W2_ELEMS + 255) / 256, 256, 0, stream>>>(
        root1, W1, root2, W2, Wt1, Wt2);
    k_cvt_x<<<(N_NODES * 32 + 255) / 256, 256, 0, stream>>>(x, xb, N_NODES * 32);

    const dim3 GG((NCHUNK * 4 + 255) / 256, R_REL);  // (782, 8)
    const int MB = (NCHUNK + 31) / 32;               // 1563

    // layer 1
    k_gather<<<GG, 256, 0, stream>>>(xb, offs, srcS, agg);
    k_gemm<128, true, true><<<MB, 256, 0, stream>>>(xb, agg, Wt1, b1, hb, nullptr);
    // layer 2
    k_gather<<<GG, 256, 0, stream>>>(hb, offs, srcS, agg);
    k_gemm<64, false, false><<<MB, 256, 0, stream>>>(hb, agg, Wt2, b2, nullptr, out);
}

// Round 11
// 260.468 us; speedup vs baseline: 2.0222x; 1.1908x over previous
//
#include <hip/hip_runtime.h>

#define N_NODES 50000
#define N_EDGES 800000
#define R_REL   8
#define NR      (N_NODES * R_REL)        // 400000
#define SCAN_CHUNK 2048
#define SCAN_NBLK  ((NR + SCAN_CHUNK - 1) / SCAN_CHUNK)   // 196

// bucketed CSR build
#define NBKT    196                      // buckets of 256 dst-nodes
#define BNSH    8                        // dst>>8 -> bucket
#define BKEYS   2048                     // keys per bucket (256 nodes x 8 rels)
#define BCAP    5120                     // record capacity per bucket (mean 4083, +16 sigma)
#define SLAB    2048                     // edges per bin-block
#define BINBLK  ((N_EDGES + SLAB - 1) / SLAB)  // 391

typedef float  f32x4  __attribute__((ext_vector_type(4)));
typedef __bf16 bf16x8 __attribute__((ext_vector_type(8)));

__device__ __forceinline__ unsigned short f2bf(float f) {
    unsigned int u = __float_as_uint(f);
    u = (u + 0x7FFFu + ((u >> 16) & 1u)) >> 16;   // RNE
    return (unsigned short)u;
}
__device__ __forceinline__ float bflo(unsigned int u) { return __uint_as_float(u << 16); }
__device__ __forceinline__ float bfhi(unsigned int u) { return __uint_as_float(u & 0xFFFF0000u); }

__device__ __forceinline__ void acc16(float* a, uint4 u0, uint4 u1) {
    a[0]  += bflo(u0.x);   a[1]  += bfhi(u0.x);
    a[2]  += bflo(u0.y);   a[3]  += bfhi(u0.y);
    a[4]  += bflo(u0.z);   a[5]  += bfhi(u0.z);
    a[6]  += bflo(u0.w);   a[7]  += bfhi(u0.w);
    a[8]  += bflo(u1.x);   a[9]  += bfhi(u1.x);
    a[10] += bflo(u1.y);   a[11] += bfhi(u1.y);
    a[12] += bflo(u1.z);   a[13] += bfhi(u1.z);
    a[14] += bflo(u1.w);   a[15] += bfhi(u1.w);
}

// ---------------- bucketed CSR build ----------------

__global__ __launch_bounds__(256) void k_binA(
    const int* __restrict__ src, const int* __restrict__ dst,
    const int* __restrict__ et, int* __restrict__ gcur,
    uint2* __restrict__ gbin)
{
    __shared__ int hist[NBKT];
    __shared__ int base[NBKT];
    const int t = threadIdx.x;
    const int e0 = blockIdx.x * SLAB;
    for (int i = t; i < NBKT; i += 256) hist[i] = 0;
    __syncthreads();
#pragma unroll
    for (int i = 0; i < SLAB / 256; ++i) {
        int e = e0 + i * 256 + t;
        if (e < N_EDGES) atomicAdd(&hist[dst[e] >> BNSH], 1);
    }
    __syncthreads();
    for (int i = t; i < NBKT; i += 256) {
        int h = hist[i];
        base[i] = (h > 0) ? atomicAdd(&gcur[i], h) : 0;
        hist[i] = 0;   // reuse as sub-cursor
    }
    __syncthreads();
#pragma unroll
    for (int i = 0; i < SLAB / 256; ++i) {
        int e = e0 + i * 256 + t;
        if (e < N_EDGES) {
            int d = dst[e];
            int b = d >> BNSH;
            int sub = atomicAdd(&hist[b], 1);
            gbin[b * BCAP + base[b] + sub] =
                make_uint2((unsigned)src[e], (unsigned)(d * 8 + et[e]));
        }
    }
}

__global__ __launch_bounds__(256) void k_bcount(
    const int* __restrict__ gcur, const uint2* __restrict__ gbin,
    int* __restrict__ cnt)
{
    __shared__ int lc[BKEYS];
    const int t = threadIdx.x;
    const int b = blockIdx.x;
    for (int i = t; i < BKEYS; i += 256) lc[i] = 0;
    __syncthreads();
    const int n = gcur[b];
    const uint2* rec = gbin + (size_t)b * BCAP;
    const int kbase = b * BKEYS;
    for (int j = t; j < n; j += 256)
        atomicAdd(&lc[rec[j].y - kbase], 1);
    __syncthreads();
    for (int i = t; i < BKEYS; i += 256) {
        int k = kbase + i;
        if (k < NR) cnt[k] = lc[i];
    }
}

__global__ __launch_bounds__(256) void k_bscat(
    const int* __restrict__ gcur, const uint2* __restrict__ gbin,
    const int* __restrict__ offs, int* __restrict__ srcS)
{
    __shared__ int cur[BKEYS];
    const int t = threadIdx.x;
    const int b = blockIdx.x;
    for (int i = t; i < BKEYS; i += 256) cur[i] = 0;
    __syncthreads();
    const int n = gcur[b];
    const uint2* rec = gbin + (size_t)b * BCAP;
    const int kbase = b * BKEYS;
    for (int j = t; j < n; j += 256) {
        uint2 r = rec[j];
        int sub = atomicAdd(&cur[r.y - kbase], 1);
        srcS[offs[r.y] + sub] = (int)r.x;
    }
}

// ---------------- scans (exclusive prefix over cnt) ----------------

__global__ void k_scan1(const int* __restrict__ cnt, int* __restrict__ offs,
                        int* __restrict__ bsum) {
    __shared__ int sd[256];
    int t = threadIdx.x;
    int base = blockIdx.x * SCAN_CHUNK + t * 8;
    int v[8];
    int tot = 0;
#pragma unroll
    for (int i = 0; i < 8; i++) {
        int idx = base + i;
        int xv = (idx < NR) ? cnt[idx] : 0;
        v[i] = tot;
        tot += xv;
    }
    sd[t] = tot;
    __syncthreads();
    for (int off = 1; off < 256; off <<= 1) {
        int y = (t >= off) ? sd[t - off] : 0;
        __syncthreads();
        sd[t] += y;
        __syncthreads();
    }
    int excl = sd[t] - tot;
#pragma unroll
    for (int i = 0; i < 8; i++) {
        int idx = base + i;
        if (idx < NR) offs[idx] = v[i] + excl;
    }
    if (t == 255) bsum[blockIdx.x] = sd[255];
}

__global__ void k_scan2(const int* __restrict__ bsum, int* __restrict__ bsum2) {
    __shared__ int sd[256];
    int t = threadIdx.x;
    int v = (t < SCAN_NBLK) ? bsum[t] : 0;
    sd[t] = v;
    __syncthreads();
    for (int off = 1; off < 256; off <<= 1) {
        int y = (t >= off) ? sd[t - off] : 0;
        __syncthreads();
        sd[t] += y;
        __syncthreads();
    }
    bsum2[t] = sd[t] - v;
}

__global__ void k_scan3(int* __restrict__ offs, const int* __restrict__ bsum2) {
    int t = threadIdx.x;
    int b = blockIdx.x;
    int add = bsum2[b];
    int base = b * SCAN_CHUNK + t * 8;
#pragma unroll
    for (int i = 0; i < 8; i++) {
        int idx = base + i;
        if (idx < NR) offs[idx] += add;
    }
    if (b == 0 && t == 0) offs[NR] = N_EDGES;
}

// ---------------- converts ----------------

__global__ void k_cvt_x(const float* __restrict__ x, unsigned short* __restrict__ xb, int n4) {
    int i = blockIdx.x * 256 + threadIdx.x;
    if (i < n4) {
        float4 v = *(const float4*)(x + (size_t)i * 4);
        ushort4 o;
        o.x = f2bf(v.x); o.y = f2bf(v.y); o.z = f2bf(v.z); o.w = f2bf(v.w);
        *(ushort4*)(xb + (size_t)i * 4) = o;
    }
}

// Fragment-ordered weight packing:
// WtP[(((seg*4 + kk)*NBt + nb)*64 + lane)*8 + j] = B[seg][n=nb*16+(lane&15)][k=kk*32+(lane>>4)*8+j]
#define W1_ELEMS (9 * 128 * 128)   // NBt=8
#define W2_ELEMS (9 * 64 * 128)    // NBt=4
__global__ void k_wprep_all(const float* __restrict__ root1, const float* __restrict__ W1,
                            const float* __restrict__ root2, const float* __restrict__ W2,
                            unsigned short* __restrict__ Wt1, unsigned short* __restrict__ Wt2) {
    int idx = blockIdx.x * 256 + threadIdx.x;
    if (idx < W1_ELEMS) {
        int j    = idx & 7;
        int lane = (idx >> 3) & 63;
        int r    = idx >> 9;
        int nb   = r & 7;        // NBt = 8
        int r2   = r >> 3;
        int kk   = r2 & 3;
        int seg  = r2 >> 2;
        int k = kk * 32 + (lane >> 4) * 8 + j;
        int n = nb * 16 + (lane & 15);
        float v = (seg == 0) ? root1[k * 128 + n] : W1[((seg - 1) * 128 + k) * 128 + n];
        Wt1[idx] = f2bf(v);
    } else if (idx < W1_ELEMS + W2_ELEMS) {
        int i2   = idx - W1_ELEMS;
        int j    = i2 & 7;
        int lane = (i2 >> 3) & 63;
        int r    = i2 >> 9;
        int nb   = r & 3;        // NBt = 4
        int r2   = r >> 2;
        int kk   = r2 & 3;
        int seg  = r2 >> 2;
        int k = kk * 32 + (lane >> 4) * 8 + j;
        int n = nb * 16 + (lane & 15);
        float v = (seg == 0) ? root2[k * 64 + n] : W2[((seg - 1) * 128 + k) * 64 + n];
        Wt2[i2] = f2bf(v);
    }
}

// ---------------- fused gather + MFMA layer ----------------
// Block = 512 threads (8 waves), 16-node tile, 3125 blocks exact.
// Gather mapping = round-10's proven pure-gather pattern: thread = (node, rel,
// 32-feat quarter), ONE edge chain per thread, 2-edge ILP; writes As[1+rel] in
// LDS instead of agg in HBM (kills the 200-MB agg round trip per layer).
// Seg-0 (root) rows staged coalesced into As[0] by threads 0-127.
// ONE barrier; then MFMA with fragment-ordered B (1 coalesced txn per B-frag —
// the fix that round 3-6 fused kernels lacked).
// FOUT=128: wave w owns col-tile w. FOUT=64: waves 4-7 retire after barrier.

template <int FOUT, bool RELU, bool OUT_BF16>
__global__ __launch_bounds__(512) void k_fused(
    const unsigned short* __restrict__ xin,  // [N,128] bf16
    const unsigned short* __restrict__ WtP,  // fragment-ordered weights
    const float* __restrict__ bias,          // [FOUT]
    const int* __restrict__ offs,            // [NR+1]
    const int* __restrict__ srcS,            // [E]
    unsigned short* __restrict__ outb,       // [N,FOUT] bf16 (if OUT_BF16)
    float* __restrict__ outf)                // [N,FOUT] fp32 (else)
{
    constexpr int NBt = FOUT / 16;           // 8 (L1) / 4 (L2)
    __shared__ __align__(16) unsigned short As[9][16][136];  // 39.2 KB

    const int t = threadIdx.x;
    const int node0 = blockIdx.x * 16;

    // ---- seg-0 staging: threads 0-127, coalesced ----
    if (t < 128) {
        const int sr = t >> 3;
        const int sp = t & 7;
        const uint4* src = (const uint4*)(xin + (size_t)(node0 + sr) * 128 + sp * 16);
        uint4 r0 = src[0], r1 = src[1];
        uint4* d = (uint4*)&As[0][sr][sp * 16];
        d[0] = r0; d[1] = r1;
    }

    // ---- gather: one chain per thread (node, rel, quarter) ----
    {
        const int nl  = t >> 5;        // local node 0..15
        const int rel = (t >> 2) & 7;  // relation
        const int q   = t & 3;         // 32-feat quarter

        const int pair = (node0 + nl) * 8 + rel;
        const int beg = offs[pair];
        const int end = offs[pair + 1];
        const int deg = end - beg;

        const unsigned short* bx = xin + q * 32;
        float a[32];
#pragma unroll
        for (int i = 0; i < 32; ++i) a[i] = 0.f;

        int j = beg;
        for (; j + 1 < end; j += 2) {
            int s0 = srcS[j];
            int s1 = srcS[j + 1];
            const uint4* p0 = (const uint4*)(bx + (size_t)s0 * 128);
            const uint4* p1 = (const uint4*)(bx + (size_t)s1 * 128);
            uint4 v0 = p0[0], v1 = p0[1], v2 = p0[2], v3 = p0[3];
            uint4 w0 = p1[0], w1 = p1[1], w2 = p1[2], w3 = p1[3];
            acc16(a, v0, v1);
            acc16(a + 16, v2, v3);
            acc16(a, w0, w1);
            acc16(a + 16, w2, w3);
        }
        if (j < end) {
            int s = srcS[j];
            const uint4* p = (const uint4*)(bx + (size_t)s * 128);
            uint4 v0 = p[0], v1 = p[1], v2 = p[2], v3 = p[3];
            acc16(a, v0, v1);
            acc16(a + 16, v2, v3);
        }

        float scl = 1.f / (float)(deg > 1 ? deg : 1);
        unsigned int pk[16];
#pragma unroll
        for (int i = 0; i < 16; ++i)
            pk[i] = (unsigned int)f2bf(a[i * 2] * scl) |
                    ((unsigned int)f2bf(a[i * 2 + 1] * scl) << 16);
        uint4* d = (uint4*)&As[1 + rel][nl][q * 32];
        d[0] = make_uint4(pk[0],  pk[1],  pk[2],  pk[3]);
        d[1] = make_uint4(pk[4],  pk[5],  pk[6],  pk[7]);
        d[2] = make_uint4(pk[8],  pk[9],  pk[10], pk[11]);
        d[3] = make_uint4(pk[12], pk[13], pk[14], pk[15]);
    }

    __syncthreads();   // all 9 As slabs ready (the only barrier)

    // ---- MFMA phase: wave w owns col-tile w ----
    const int lane = t & 63;
    const int w = t >> 6;
    if (w >= NBt) return;            // FOUT=64: waves 4-7 done (no barriers after)
    const int quad = lane >> 4;
    const int tc = lane & 15;

    f32x4 acc = (f32x4){0.f, 0.f, 0.f, 0.f};
    const bf16x8* Bp = (const bf16x8*)WtP;

#pragma unroll
    for (int seg = 0; seg < 9; ++seg) {
        const unsigned short* Arow = &As[seg][tc][0];
#pragma unroll
        for (int kk = 0; kk < 4; ++kk) {
            bf16x8 af = *(const bf16x8*)(Arow + kk * 32 + quad * 8);
            bf16x8 bf = Bp[((seg * 4 + kk) * NBt + w) * 64 + lane];
            acc = __builtin_amdgcn_mfma_f32_16x16x32_bf16(af, bf, acc, 0, 0, 0);
        }
    }

    // epilogue: D layout col = lane&15, row = quad*4 + reg
    const int col = w * 16 + tc;
    const float bs = bias[col];
#pragma unroll
    for (int i = 0; i < 4; ++i) {
        int r = node0 + quad * 4 + i;
        float v = acc[i] + bs;
        if (RELU) v = fmaxf(v, 0.f);
        if (OUT_BF16) outb[(size_t)r * FOUT + col] = f2bf(v);
        else          outf[(size_t)r * FOUT + col] = v;
    }
}

// ---------------- launch ----------------

extern "C" void kernel_launch(void* const* d_in, const int* in_sizes, int n_in,
                              void* d_out, int out_size, void* d_ws, size_t ws_size,
                              hipStream_t stream) {
    const float* x     = (const float*)d_in[0];
    const int*   ei    = (const int*)d_in[1];  // [2][E]: row0=src, row1=dst
    const int*   et    = (const int*)d_in[2];  // [E]
    const float* W1    = (const float*)d_in[3];
    const float* root1 = (const float*)d_in[4];
    const float* b1    = (const float*)d_in[5];
    const float* W2    = (const float*)d_in[6];
    const float* root2 = (const float*)d_in[7];
    const float* b2    = (const float*)d_in[8];
    float* out = (float*)d_out;

    int* ws     = (int*)d_ws;
    int* cnt    = ws;                  // NR        (reused for Wt1 after scan1)
    int* offs   = cnt + NR;            // NR+128
    int* wt2buf = offs + NR + 128;     // NR        (holds Wt2, 144 KB)
    int* bsum   = wt2buf + NR;         // 256
    int* bsum2  = bsum + 256;          // 256
    int* gcur   = bsum2 + 256;         // 256
    int* srcS   = gcur + 256;          // E
    unsigned short* xb  = (unsigned short*)(srcS + N_EDGES); // [N,128] bf16 (12.8 MB)
    unsigned short* hb  = xb + (size_t)N_NODES * 128;        // [N,128] bf16 (12.8 MB)
    uint2* gbin = (uint2*)(hb + (size_t)N_NODES * 128);      // 8.03 MB
    unsigned short* Wt1 = (unsigned short*)cnt;
    unsigned short* Wt2 = (unsigned short*)wt2buf;
    // total ws usage: ~8 MB ints + 12.8 + 12.8 + 8 = ~42 MB (ws = 256 MiB)

    hipMemsetAsync(gcur, 0, 256 * sizeof(int), stream);
    k_binA<<<BINBLK, 256, 0, stream>>>(ei, ei + N_EDGES, et, gcur, gbin);
    k_bcount<<<NBKT, 256, 0, stream>>>(gcur, gbin, cnt);
    k_scan1<<<SCAN_NBLK, 256, 0, stream>>>(cnt, offs, bsum);
    k_scan2<<<1, 256, 0, stream>>>(bsum, bsum2);
    k_scan3<<<SCAN_NBLK, 256, 0, stream>>>(offs, bsum2);
    k_bscat<<<NBKT, 256, 0, stream>>>(gcur, gbin, offs, srcS);

    // cnt dead after scan1 -> Wt1 overwrites; wt2buf never aliased
    k_wprep_all<<<(W1_ELEMS + W2_ELEMS + 255) / 256, 256, 0, stream>>>(
        root1, W1, root2, W2, Wt1, Wt2);
    k_cvt_x<<<(N_NODES * 32 + 255) / 256, 256, 0, stream>>>(x, xb, N_NODES * 32);

    const int NT = N_NODES / 16;  // 3125 exactly

    k_fused<128, true,  true ><<<NT, 512, 0, stream>>>(xb, Wt1, b1, offs, srcS, hb, nullptr);
    k_fused<64,  false, false><<<NT, 512, 0, stream>>>(hb, Wt2, b2, offs, srcS, nullptr, out);
}